// Round 4
// baseline (101.496 us; speedup 1.0000x reference)
//
#include <hip/hip_runtime.h>

// SGCN fused: out[n,d,t,w] = sum_v (sum_c x[n,c,t,v]*W[c,d] + b[d]) * a[n,t,v,w]
// plus exact f32 copy of a into d_out second region.
// N=64, C_IN=C_OUT=64, T=300, V=25.
// Block = 512 threads (8 waves), handles (n, t0..t0+3).
// Wave wid: tl = wid>>1 (t index), dh = wid&1 (32-row d-half).
// LDS 27KB: Xs (x^T slices) aliased with per-wave Ys after barrier2; At separate.
// W fragments are built straight from global (L2-resident, no LDS).

typedef __attribute__((ext_vector_type(8))) short short8;
typedef __attribute__((ext_vector_type(4))) float f32x4;

#define XS_S 66   // Xs row stride (ushort)
#define YS_S 36   // Ys row stride
#define AT_S 36   // At row stride

__device__ __forceinline__ unsigned short f2bf(float f) {
    unsigned int u = __builtin_bit_cast(unsigned int, f);
    return (unsigned short)((u + 0x7FFFu + ((u >> 16) & 1u)) >> 16);
}

__global__ __launch_bounds__(512, 8)
void sgcn_fused(const float* __restrict__ xg, const float* __restrict__ ag,
                const float* __restrict__ Wg, const float* __restrict__ bg,
                float* __restrict__ outg)
{
    // Union region: Xs[4][32*XS_S] = 8448 shorts (live until barrier2),
    // then Ys[8][32*YS_S] = 9216 shorts. At is separate (live whole kernel).
    __shared__ alignas(16) unsigned short Ubuf[9216];
    __shared__ alignas(16) unsigned short At[4 * 32 * AT_S];

    const int tid  = threadIdx.x;
    const int wid  = tid >> 6;
    const int lane = tid & 63;
    const int q    = lane >> 4;   // 0..3
    const int lo   = lane & 15;   // 0..15

    const int bid = blockIdx.x;
    const int n   = bid / 75;
    const int t0  = (bid % 75) * 4;

    // ---------------- issue x/a global loads (independent, early) ----------
    // x slab: 64 c-rows x 100 floats (4 t's) = 1600 float4
    f32x4 xv[4];
    const long xbase = ((long)n * 64 * 300 + t0) * 25;
#pragma unroll
    for (int m = 0; m < 4; ++m) {
        const int f = tid + 512 * m;
        if (m < 3 || f < 1600) {
            const int c = f / 25, j = f % 25;
            xv[m] = *(const f32x4*)(xg + xbase + (long)c * 7500 + 4 * j);
        }
    }
    // a slab: 2500 floats = 625 float4
    f32x4 av[2];
    const long abase = ((long)n * 300 + t0) * 625;
#pragma unroll
    for (int m = 0; m < 2; ++m) {
        const int f = tid + 512 * m;
        if (m < 1 || f < 625)
            av[m] = *(const f32x4*)(ag + abase + 4 * f);
    }

    // ---------------- zero At pad columns v=25..31 (K-dim of step 2) -------
    if (tid < 128) {   // 4 tl * 32 w-rows
        unsigned short* ar = &At[(tid >> 5) * 32 * AT_S + (tid & 31) * AT_S];
#pragma unroll
        for (int i = 25; i < 32; ++i) ar[i] = 0;
    }

    // ---------------- scatter to LDS (bf16) --------------------------------
    // x -> Xs[tl][v][c]
    {
        unsigned short* Xs0 = Ubuf;
#pragma unroll
        for (int m = 0; m < 4; ++m) {
            const int f = tid + 512 * m;
            if (m < 3 || f < 1600) {
                const int c = f / 25, j = f % 25;
#pragma unroll
                for (int i = 0; i < 4; ++i) {
                    const int e = 4 * j + i;          // 0..99 within the 4-t row
                    const int tl = e / 25, v = e % 25;
                    Xs0[tl * (32 * XS_S) + v * XS_S + c] = f2bf(xv[m][i]);
                }
            }
        }
    }
    // a -> f32 copy to out + At[tl][w][v]
    {
        float* aout = outg + 30720000L + abase;
#pragma unroll
        for (int m = 0; m < 2; ++m) {
            const int f = tid + 512 * m;
            if (m < 1 || f < 625) {
                *(f32x4*)(aout + 4 * f) = av[m];
#pragma unroll
                for (int i = 0; i < 4; ++i) {
                    const int e = 4 * f + i;       // (t,v,w) flat
                    const int tl = e / 625, r = e % 625;
                    At[tl * (32 * AT_S) + (r % 25) * AT_S + (r / 25)] = f2bf(av[m][i]);
                }
            }
        }
    }

    // ---------------- W fragments straight from global (L2-hit) ------------
    const int tl = wid >> 1;
    const int dh = wid & 1;
    const int t  = t0 + tl;
    const int d0 = 32 * dh;

    short8 wfrag[2][2];
#pragma unroll
    for (int mi = 0; mi < 2; ++mi)
#pragma unroll
        for (int ki = 0; ki < 2; ++ki) {
            const int d = d0 + 16 * mi + lo;
#pragma unroll
            for (int i = 0; i < 8; ++i) {
                const int c = 32 * ki + 8 * q + i;
                wfrag[mi][ki][i] = (short)f2bf(Wg[c * 64 + d]);
            }
        }

    f32x4 bias[2];
#pragma unroll
    for (int mi = 0; mi < 2; ++mi)
#pragma unroll
        for (int r = 0; r < 4; ++r)
            bias[mi][r] = bg[d0 + 16 * mi + 4 * q + r];

    __syncthreads();   // barrier1: staging complete

    // ---------------- step 1: y = W^T x + b  (M=32, N=32pad, K=64) ---------
    const unsigned short* xs = Ubuf + tl * (32 * XS_S);

    f32x4 accy[2][2];
#pragma unroll
    for (int mi = 0; mi < 2; ++mi) { accy[mi][0] = bias[mi]; accy[mi][1] = bias[mi]; }
#pragma unroll
    for (int ni = 0; ni < 2; ++ni)
#pragma unroll
        for (int ki = 0; ki < 2; ++ki) {
            const short8 bf = *(const short8*)&xs[(16 * ni + lo) * XS_S + 32 * ki + 8 * q];
#pragma unroll
            for (int mi = 0; mi < 2; ++mi)
                accy[mi][ni] = __builtin_amdgcn_mfma_f32_16x16x32_bf16(
                    wfrag[mi][ki], bf, accy[mi][ni], 0, 0, 0);
        }

    __syncthreads();   // barrier2: all Xs reads done; Ubuf becomes Ys

    // ---------------- y -> Ys[dlocal][v] (bf16, pad cols -> 0) -------------
    unsigned short* ys = Ubuf + wid * (32 * YS_S);
#pragma unroll
    for (int mi = 0; mi < 2; ++mi)
#pragma unroll
        for (int ni = 0; ni < 2; ++ni) {
            const int v = 16 * ni + lo;
            const bool ok = (v < 25);
#pragma unroll
            for (int r = 0; r < 4; ++r)
                ys[(16 * mi + 4 * q + r) * YS_S + v] =
                    ok ? f2bf(accy[mi][ni][r]) : (unsigned short)0;
        }

    // ---------------- step 2 (swapped): O^T[w,d] = a^T[w,:] . y[d,:] -------
    const unsigned short* at = At + tl * (32 * AT_S);
    short8 afr[2];
#pragma unroll
    for (int mi = 0; mi < 2; ++mi)
        afr[mi] = *(const short8*)&at[(16 * mi + lo) * AT_S + 8 * q];
    short8 yfr[2];
#pragma unroll
    for (int dj = 0; dj < 2; ++dj)
        yfr[dj] = *(const short8*)&ys[(16 * dj + lo) * YS_S + 8 * q];

    f32x4 acco[2][2];
#pragma unroll
    for (int mi = 0; mi < 2; ++mi)
#pragma unroll
        for (int dj = 0; dj < 2; ++dj)
            acco[mi][dj] = f32x4{0.f, 0.f, 0.f, 0.f};
#pragma unroll
    for (int mi = 0; mi < 2; ++mi)
#pragma unroll
        for (int dj = 0; dj < 2; ++dj)
            acco[mi][dj] = __builtin_amdgcn_mfma_f32_16x16x32_bf16(
                afr[mi], yfr[dj], acco[mi][dj], 0, 0, 0);

    // ---------------- store out[n,d,t,w]; lane's 4 regs = consecutive w ----
    float* op = outg + ((long)n * 64 * 300 + t) * 25;
#pragma unroll
    for (int dj = 0; dj < 2; ++dj) {
        const long dbase = (long)(d0 + 16 * dj + lo) * 7500;
        *(f32x4*)(op + dbase + 4 * q) = acco[0][dj];          // w = 4q..4q+3
        if (q < 2)
            *(f32x4*)(op + dbase + 16 + 4 * q) = acco[1][dj]; // w = 16..23
        else if (q == 2)
            op[dbase + 24] = acco[1][dj][0];                  // w = 24
    }
}

extern "C" void kernel_launch(void* const* d_in, const int* in_sizes, int n_in,
                              void* d_out, int out_size, void* d_ws, size_t ws_size,
                              hipStream_t stream) {
    const float* x = (const float*)d_in[0];
    const float* a = (const float*)d_in[1];
    const float* W = (const float*)d_in[2];
    const float* b = (const float*)d_in[3];
    float* out = (float*)d_out;
    hipLaunchKernelGGL(sgcn_fused, dim3(64 * 75), dim3(512), 0, stream,
                       x, a, W, b, out);
}

// Round 5
// 79.595 us; speedup vs baseline: 1.2752x; 1.2752x over previous
//
#include <hip/hip_runtime.h>

// SGCN fused: out[n,d,t,w] = sum_v (sum_c x[n,c,t,v]*W[c,d] + b[d]) * a[n,t,v,w]
// plus exact f32 copy of a into d_out second region.
// N=64, C_IN=C_OUT=64, T=300, V=25.
// Block = 512 threads (8 waves), handles (n, t0..t0+3).
// Wave wid: tl = wid>>1 (t index), dh = wid&1 (32-row d-half).
// LDS 36KB: Wt + At + Ubuf{Xs -> (barrier2) -> per-wave Ys}.  4 blocks/CU.

typedef __attribute__((ext_vector_type(8))) short short8;
typedef __attribute__((ext_vector_type(4))) float f32x4;

#define XS_S 66   // Wt/Xs row stride (ushort)
#define YS_S 36   // Ys row stride
#define AT_S 36   // At row stride

__device__ __forceinline__ unsigned short f2bf(float f) {
    unsigned int u = __builtin_bit_cast(unsigned int, f);
    return (unsigned short)((u + 0x7FFFu + ((u >> 16) & 1u)) >> 16);
}

__global__ __launch_bounds__(512, 6)
void sgcn_fused(const float* __restrict__ xg, const float* __restrict__ ag,
                const float* __restrict__ Wg, const float* __restrict__ bg,
                float* __restrict__ outg)
{
    __shared__ alignas(16) unsigned short Wt[64 * XS_S];   // W^T [d][c], whole kernel
    __shared__ alignas(16) unsigned short At[4 * 32 * AT_S]; // a^T [tl][w][v], whole kernel
    // Union: Xs[4][32*XS_S] = 8448 shorts until barrier2, then Ys[8][32*YS_S] = 9216.
    __shared__ alignas(16) unsigned short Ubuf[9216];

    const int tid  = threadIdx.x;
    const int wid  = tid >> 6;
    const int lane = tid & 63;
    const int q    = lane >> 4;   // 0..3
    const int lo   = lane & 15;   // 0..15

    const int bid = blockIdx.x;
    const int n   = bid / 75;
    const int t0  = (bid % 75) * 4;

    // ---------------- issue all global loads (independent, early) ----------
    // x slab: 64 c-rows x 100 floats (4 t's) = 1600 float4
    f32x4 xv[4];
    const long xbase = ((long)n * 64 * 300 + t0) * 25;
#pragma unroll
    for (int m = 0; m < 4; ++m) {
        const int f = tid + 512 * m;
        if (m < 3 || f < 1600) {
            const int c = f / 25, j = f % 25;
            xv[m] = *(const f32x4*)(xg + xbase + (long)c * 7500 + 4 * j);
        }
    }
    // a slab: 2500 floats = 625 float4
    f32x4 av[2];
    const long abase = ((long)n * 300 + t0) * 625;
#pragma unroll
    for (int m = 0; m < 2; ++m) {
        const int f = tid + 512 * m;
        if (m < 1 || f < 625)
            av[m] = *(const f32x4*)(ag + abase + 4 * f);
    }
    // W: 4096 floats = 1024 float4
    f32x4 wv[2];
#pragma unroll
    for (int m = 0; m < 2; ++m)
        wv[m] = *(const f32x4*)(Wg + 4 * (tid + 512 * m));

    // ---------------- zero At pad columns v=25..31 (K-dim of step 2) -------
    if (tid < 128) {   // 4 tl * 32 w-rows
        unsigned short* ar = &At[(tid >> 5) * (32 * AT_S) + (tid & 31) * AT_S];
#pragma unroll
        for (int i = 25; i < 32; ++i) ar[i] = 0;
    }

    // ---------------- scatter to LDS (bf16) --------------------------------
    // W -> Wt[d][c]
#pragma unroll
    for (int m = 0; m < 2; ++m) {
        const int f = 4 * (tid + 512 * m);
#pragma unroll
        for (int i = 0; i < 4; ++i) {
            const int e = f + i, c = e >> 6, d = e & 63;
            Wt[d * XS_S + c] = f2bf(wv[m][i]);
        }
    }
    // x -> Xs[tl][v][c]
#pragma unroll
    for (int m = 0; m < 4; ++m) {
        const int f = tid + 512 * m;
        if (m < 3 || f < 1600) {
            const int c = f / 25, j = f % 25;
#pragma unroll
            for (int i = 0; i < 4; ++i) {
                const int e = 4 * j + i;          // 0..99 within the 4-t row
                const int tl = e / 25, v = e % 25;
                Ubuf[tl * (32 * XS_S) + v * XS_S + c] = f2bf(xv[m][i]);
            }
        }
    }
    // a -> f32 copy to out + At[tl][w][v]
    {
        float* aout = outg + 30720000L + abase;
#pragma unroll
        for (int m = 0; m < 2; ++m) {
            const int f = tid + 512 * m;
            if (m < 1 || f < 625) {
                *(f32x4*)(aout + 4 * f) = av[m];
#pragma unroll
                for (int i = 0; i < 4; ++i) {
                    const int e = 4 * f + i;       // (t,v,w) flat
                    const int tl = e / 625, r = e % 625;
                    At[tl * (32 * AT_S) + (r % 25) * AT_S + (r / 25)] = f2bf(av[m][i]);
                }
            }
        }
    }
    __syncthreads();   // barrier1: staging complete

    // ---------------- per-wave compute: t = t0 + tl, d in [32*dh, 32*dh+32) -
    const int tl = wid >> 1;
    const int dh = wid & 1;
    const int t  = t0 + tl;
    const int d0 = 32 * dh;

    short8 wfrag[2][2];
#pragma unroll
    for (int mi = 0; mi < 2; ++mi)
#pragma unroll
        for (int ki = 0; ki < 2; ++ki)
            wfrag[mi][ki] = *(const short8*)&Wt[(d0 + 16 * mi + lo) * XS_S + 32 * ki + 8 * q];

    f32x4 bias[2];
#pragma unroll
    for (int mi = 0; mi < 2; ++mi)
#pragma unroll
        for (int r = 0; r < 4; ++r)
            bias[mi][r] = bg[d0 + 16 * mi + 4 * q + r];

    // step 1: y[dlocal,v] = b + sum_c W[c,d] x[c,v]   (M=32, N=32pad, K=64)
    const unsigned short* xs = Ubuf + tl * (32 * XS_S);
    f32x4 accy[2][2];
#pragma unroll
    for (int mi = 0; mi < 2; ++mi) { accy[mi][0] = bias[mi]; accy[mi][1] = bias[mi]; }
#pragma unroll
    for (int ni = 0; ni < 2; ++ni)
#pragma unroll
        for (int ki = 0; ki < 2; ++ki) {
            const short8 bf = *(const short8*)&xs[(16 * ni + lo) * XS_S + 32 * ki + 8 * q];
#pragma unroll
            for (int mi = 0; mi < 2; ++mi)
                accy[mi][ni] = __builtin_amdgcn_mfma_f32_16x16x32_bf16(
                    wfrag[mi][ki], bf, accy[mi][ni], 0, 0, 0);
        }

    __syncthreads();   // barrier2: all Xs reads done; Ubuf becomes Ys

    // y -> Ys[dlocal][v] (bf16, pad cols -> 0); D layout: lane holds D[16mi+4q+r][16ni+lo]
    unsigned short* ys = Ubuf + wid * (32 * YS_S);
#pragma unroll
    for (int mi = 0; mi < 2; ++mi)
#pragma unroll
        for (int ni = 0; ni < 2; ++ni) {
            const int v = 16 * ni + lo;
            const bool ok = (v < 25);
#pragma unroll
            for (int r = 0; r < 4; ++r)
                ys[(16 * mi + 4 * q + r) * YS_S + v] =
                    ok ? f2bf(accy[mi][ni][r]) : (unsigned short)0;
        }

    // step 2 (swapped): O^T[w, dlocal] = sum_v a^T[w,v] * y[dlocal,v]
    const unsigned short* at = At + tl * (32 * AT_S);
    short8 afr[2];
#pragma unroll
    for (int mi = 0; mi < 2; ++mi)
        afr[mi] = *(const short8*)&at[(16 * mi + lo) * AT_S + 8 * q];
    short8 yfr[2];
#pragma unroll
    for (int dj = 0; dj < 2; ++dj)
        yfr[dj] = *(const short8*)&ys[(16 * dj + lo) * YS_S + 8 * q];

    f32x4 acco[2][2];
#pragma unroll
    for (int mi = 0; mi < 2; ++mi)
#pragma unroll
        for (int dj = 0; dj < 2; ++dj)
            acco[mi][dj] = f32x4{0.f, 0.f, 0.f, 0.f};
#pragma unroll
    for (int mi = 0; mi < 2; ++mi)
#pragma unroll
        for (int dj = 0; dj < 2; ++dj)
            acco[mi][dj] = __builtin_amdgcn_mfma_f32_16x16x32_bf16(
                afr[mi], yfr[dj], acco[mi][dj], 0, 0, 0);

    // store: D[row = w = 16mi+4q+r][col = dlocal = 16dj+lo] -> out[n, d, t, w]
    float* op = outg + ((long)n * 64 * 300 + t) * 25;
#pragma unroll
    for (int dj = 0; dj < 2; ++dj) {
        const long dbase = (long)(d0 + 16 * dj + lo) * 7500;
        *(f32x4*)(op + dbase + 4 * q) = acco[0][dj];          // w = 4q..4q+3
        if (q < 2)
            *(f32x4*)(op + dbase + 16 + 4 * q) = acco[1][dj]; // w = 16..23
        else if (q == 2)
            op[dbase + 24] = acco[1][dj][0];                  // w = 24
    }
}

extern "C" void kernel_launch(void* const* d_in, const int* in_sizes, int n_in,
                              void* d_out, int out_size, void* d_ws, size_t ws_size,
                              hipStream_t stream) {
    const float* x = (const float*)d_in[0];
    const float* a = (const float*)d_in[1];
    const float* W = (const float*)d_in[2];
    const float* b = (const float*)d_in[3];
    float* out = (float*)d_out;
    hipLaunchKernelGGL(sgcn_fused, dim3(64 * 75), dim3(512), 0, stream,
                       x, a, W, b, out);
}